// Round 4
// baseline (46.545 us; speedup 1.0000x reference)
//
#include <hip/hip_runtime.h>
#include <math.h>

// GENPool: segment softmax aggregation (batch sorted), then s*n/(1+beta*(n-1)).
// One block per segment. Each thread owns 4 consecutive features (float4 lane),
// 16 row-splits per block, online softmax per (feature, split), LDS merge.

constexpr int F      = 256;          // feature dim
constexpr int VEC    = 4;            // float4
constexpr int FT     = F / VEC;      // 64 feature-groups -> one wave spans a row
constexpr int SPLITS = 16;           // row-parallel splits
constexpr int BLOCK  = FT * SPLITS;  // 1024 threads = 16 waves; 2 blocks/CU

// online-softmax accumulate of v into (m, d, s); exp(-inf)=0 handles first iter
__device__ __forceinline__ void proc(float v, float p, float& m, float& d, float& s)
{
    float a  = p * v;
    float mn = fmaxf(m, a);
    float c  = __expf(m - mn);
    float w  = __expf(a - mn);
    d = fmaf(d, c, w);
    s = fmaf(s, c, v * w);
    m = mn;
}

#define PROC4(v)                                  \
    do {                                          \
        proc((v).x, p, m[0], d[0], s[0]);         \
        proc((v).y, p, m[1], d[1], s[1]);         \
        proc((v).z, p, m[2], d[2], s[2]);         \
        proc((v).w, p, m[3], d[3], s[3]);         \
    } while (0)

__global__ __launch_bounds__(BLOCK, 8) void genpool_kernel(
    const float4* __restrict__ x4,     // [N][FT] float4
    const int*    __restrict__ batch,  // [N] sorted
    const float*  __restrict__ p_ptr,
    const float*  __restrict__ beta_ptr,
    float4*       __restrict__ out4,   // [B][FT]
    int N)
{
    const int b     = blockIdx.x;
    const int tid   = threadIdx.x;
    const int f4    = tid & (FT - 1);
    const int split = tid >> 6;        // FT == 64

    const float p    = p_ptr[0];
    const float beta = beta_ptr[0];

    // Interleaved dual binary search: start = lb(b), end = lb(b+1).
    int lo0 = 0, hi0 = N, lo1 = 0, hi1 = N;
    while (lo0 < hi0 || lo1 < hi1) {
        int m0 = (lo0 + hi0) >> 1;
        int m1 = (lo1 + hi1) >> 1;
        int v0 = (lo0 < hi0) ? batch[m0] : 0;
        int v1 = (lo1 < hi1) ? batch[m1] : 0;
        if (lo0 < hi0) { if (v0 < b)     lo0 = m0 + 1; else hi0 = m0; }
        if (lo1 < hi1) { if (v1 < b + 1) lo1 = m1 + 1; else hi1 = m1; }
    }
    const int start = lo0;
    const int end   = lo1;

    // Per-thread online softmax state for 4 features (static indexing only).
    float m[VEC], d[VEC], s[VEC];
#pragma unroll
    for (int j = 0; j < VEC; ++j) { m[j] = -INFINITY; d[j] = 0.f; s[j] = 0.f; }

    int i = start + split;
    // 4-deep load batching: 4 x float4 = 64 B in flight per thread.
    for (; i + 3 * SPLITS < end; i += 4 * SPLITS) {
        float4 v0 = x4[(size_t)(i + 0 * SPLITS) * FT + f4];
        float4 v1 = x4[(size_t)(i + 1 * SPLITS) * FT + f4];
        float4 v2 = x4[(size_t)(i + 2 * SPLITS) * FT + f4];
        float4 v3 = x4[(size_t)(i + 3 * SPLITS) * FT + f4];
        PROC4(v0); PROC4(v1); PROC4(v2); PROC4(v3);
    }
    for (; i < end; i += SPLITS) {
        float4 v = x4[(size_t)i * FT + f4];
        PROC4(v);
    }

    // Merge 16 splits per feature via LDS (3 x 16 KB = 48 KB).
    __shared__ float4 sm4[SPLITS][FT];
    __shared__ float4 sd4[SPLITS][FT];
    __shared__ float4 ss4[SPLITS][FT];
    sm4[split][f4] = make_float4(m[0], m[1], m[2], m[3]);
    sd4[split][f4] = make_float4(d[0], d[1], d[2], d[3]);
    ss4[split][f4] = make_float4(s[0], s[1], s[2], s[3]);
    __syncthreads();

    if (tid < FT) {
        // Pass 1: global max per feature (avoids exp(nan) from -inf partials).
        float M[VEC];
#pragma unroll
        for (int j = 0; j < VEC; ++j) M[j] = -INFINITY;
        for (int k = 0; k < SPLITS; ++k) {
            float4 km = sm4[k][tid];
            M[0] = fmaxf(M[0], km.x); M[1] = fmaxf(M[1], km.y);
            M[2] = fmaxf(M[2], km.z); M[3] = fmaxf(M[3], km.w);
        }
        // Pass 2: rescale-accumulate. Empty split: exp(-inf - M) = 0 for finite M.
        float D[VEC] = {0.f, 0.f, 0.f, 0.f};
        float S[VEC] = {0.f, 0.f, 0.f, 0.f};
        for (int k = 0; k < SPLITS; ++k) {
            float4 km = sm4[k][tid];
            float4 kd = sd4[k][tid];
            float4 ks = ss4[k][tid];
            float c0 = __expf(km.x - M[0]);
            float c1 = __expf(km.y - M[1]);
            float c2 = __expf(km.z - M[2]);
            float c3 = __expf(km.w - M[3]);
            D[0] = fmaf(kd.x, c0, D[0]); S[0] = fmaf(ks.x, c0, S[0]);
            D[1] = fmaf(kd.y, c1, D[1]); S[1] = fmaf(ks.y, c1, S[1]);
            D[2] = fmaf(kd.z, c2, D[2]); S[2] = fmaf(ks.z, c2, S[2]);
            D[3] = fmaf(kd.w, c3, D[3]); S[3] = fmaf(ks.w, c3, S[3]);
        }

        const float cnt = (float)(end - start);
        float4 o = make_float4(0.f, 0.f, 0.f, 0.f);
        if (cnt > 0.f) {
            const float scale = cnt / (1.f + beta * (cnt - 1.f));
            o.x = S[0] / D[0] * scale;
            o.y = S[1] / D[1] * scale;
            o.z = S[2] / D[2] * scale;
            o.w = S[3] / D[3] * scale;
        }
        out4[(size_t)b * FT + tid] = o;
    }
}

extern "C" void kernel_launch(void* const* d_in, const int* in_sizes, int n_in,
                              void* d_out, int out_size, void* d_ws, size_t ws_size,
                              hipStream_t stream)
{
    const float4* x4    = (const float4*)d_in[0];
    const int*    batch = (const int*)d_in[1];
    const float*  p     = (const float*)d_in[2];
    const float*  beta  = (const float*)d_in[3];
    float4* out4 = (float4*)d_out;

    const int N = in_sizes[1];     // 200000 rows
    const int B = out_size / F;    // 512 segments

    genpool_kernel<<<B, BLOCK, 0, stream>>>(x4, batch, p, beta, out4, N);
}

// Round 5
// 41.523 us; speedup vs baseline: 1.1210x; 1.1210x over previous
//
#include <hip/hip_runtime.h>
#include <math.h>

// GENPool: segment softmax aggregation (batch sorted), then s*n/(1+beta*(n-1)).
// One block per segment. float2 lanes (8 B/lane, light registers), 8 row-splits,
// 4-deep load batching, online softmax per (feature, split), LDS merge.

constexpr int F      = 256;          // feature dim
constexpr int VEC    = 2;            // float2 per lane
constexpr int FT     = F / VEC;      // 128 feature-groups per row
constexpr int SPLITS = 8;            // row-parallel splits
constexpr int BLOCK  = FT * SPLITS;  // 1024 threads = 16 waves; 2 blocks/CU

// online-softmax accumulate of v into (m, d, s); exp(-inf)=0 handles first iter
__device__ __forceinline__ void proc(float v, float p, float& m, float& d, float& s)
{
    float a  = p * v;
    float mn = fmaxf(m, a);
    float c  = __expf(m - mn);
    float w  = __expf(a - mn);
    d = fmaf(d, c, w);
    s = fmaf(s, c, v * w);
    m = mn;
}

#define PROC2(v)                              \
    do {                                      \
        proc((v).x, p, m0, d0, s0);           \
        proc((v).y, p, m1, d1, s1);           \
    } while (0)

__global__ __launch_bounds__(BLOCK, 8) void genpool_kernel(
    const float2* __restrict__ x2,     // [N][FT] float2
    const int*    __restrict__ batch,  // [N] sorted
    const float*  __restrict__ p_ptr,
    const float*  __restrict__ beta_ptr,
    float2*       __restrict__ out2,   // [B][FT]
    int N)
{
    const int b     = blockIdx.x;
    const int tid   = threadIdx.x;
    const int f2    = tid & (FT - 1);
    const int split = tid >> 7;        // FT == 128

    const float p    = p_ptr[0];
    const float beta = beta_ptr[0];

    // Interleaved dual binary search: start = lb(b), end = lb(b+1).
    int lo0 = 0, hi0 = N, lo1 = 0, hi1 = N;
    while (lo0 < hi0 || lo1 < hi1) {
        int m0i = (lo0 + hi0) >> 1;
        int m1i = (lo1 + hi1) >> 1;
        int v0 = (lo0 < hi0) ? batch[m0i] : 0;
        int v1 = (lo1 < hi1) ? batch[m1i] : 0;
        if (lo0 < hi0) { if (v0 < b)     lo0 = m0i + 1; else hi0 = m0i; }
        if (lo1 < hi1) { if (v1 < b + 1) lo1 = m1i + 1; else hi1 = m1i; }
    }
    const int start = lo0;
    const int end   = lo1;

    // Per-thread online softmax state for 2 features (scalars -> registers).
    float m0 = -INFINITY, d0 = 0.f, s0 = 0.f;
    float m1 = -INFINITY, d1 = 0.f, s1 = 0.f;

    int i = start + split;
    // 4-deep load batching: 4 x float2 = 32 B in flight per thread.
    for (; i + 3 * SPLITS < end; i += 4 * SPLITS) {
        float2 v0 = x2[(size_t)(i + 0 * SPLITS) * FT + f2];
        float2 v1 = x2[(size_t)(i + 1 * SPLITS) * FT + f2];
        float2 v2 = x2[(size_t)(i + 2 * SPLITS) * FT + f2];
        float2 v3 = x2[(size_t)(i + 3 * SPLITS) * FT + f2];
        PROC2(v0); PROC2(v1); PROC2(v2); PROC2(v3);
    }
    for (; i < end; i += SPLITS) {
        float2 v = x2[(size_t)i * FT + f2];
        PROC2(v);
    }

    // Merge 8 splits per feature via LDS (3 x 8 KB = 24 KB).
    __shared__ float2 sm2[SPLITS][FT];
    __shared__ float2 sd2[SPLITS][FT];
    __shared__ float2 ss2[SPLITS][FT];
    sm2[split][f2] = make_float2(m0, m1);
    sd2[split][f2] = make_float2(d0, d1);
    ss2[split][f2] = make_float2(s0, s1);
    __syncthreads();

    if (tid < FT) {
        // Pass 1: global max per feature (avoids exp(nan) from -inf partials).
        float M0 = -INFINITY, M1 = -INFINITY;
        for (int k = 0; k < SPLITS; ++k) {
            float2 km = sm2[k][tid];
            M0 = fmaxf(M0, km.x);
            M1 = fmaxf(M1, km.y);
        }
        // Pass 2: rescale-accumulate. Empty split: exp(-inf - M) = 0 for finite M.
        float D0 = 0.f, S0 = 0.f, D1 = 0.f, S1 = 0.f;
        for (int k = 0; k < SPLITS; ++k) {
            float2 km = sm2[k][tid];
            float2 kd = sd2[k][tid];
            float2 ks = ss2[k][tid];
            float c0 = __expf(km.x - M0);
            float c1 = __expf(km.y - M1);
            D0 = fmaf(kd.x, c0, D0); S0 = fmaf(ks.x, c0, S0);
            D1 = fmaf(kd.y, c1, D1); S1 = fmaf(ks.y, c1, S1);
        }

        const float cnt = (float)(end - start);
        float2 o = make_float2(0.f, 0.f);
        if (cnt > 0.f) {
            const float scale = cnt / (1.f + beta * (cnt - 1.f));
            o.x = S0 / D0 * scale;
            o.y = S1 / D1 * scale;
        }
        out2[(size_t)b * FT + tid] = o;
    }
}

extern "C" void kernel_launch(void* const* d_in, const int* in_sizes, int n_in,
                              void* d_out, int out_size, void* d_ws, size_t ws_size,
                              hipStream_t stream)
{
    const float2* x2    = (const float2*)d_in[0];
    const int*    batch = (const int*)d_in[1];
    const float*  p     = (const float*)d_in[2];
    const float*  beta  = (const float*)d_in[3];
    float2* out2 = (float2*)d_out;

    const int N = in_sizes[1];     // 200000 rows
    const int B = out_size / F;    // 512 segments

    genpool_kernel<<<B, BLOCK, 0, stream>>>(x2, batch, p, beta, out2, N);
}